// Round 11
// baseline (508.878 us; speedup 1.0000x reference)
//
#include <hip/hip_runtime.h>

#define NN 50000
#define NE 800000
#define IND 64
#define HID 128
#define NG 1024

#define NBK 391   // buckets of 128 dst nodes
#define BCAP 2560 // padded capacity per bucket (avg 2046, +11 sigma)

typedef short bf16x8 __attribute__((ext_vector_type(8)));
typedef float f32x4 __attribute__((ext_vector_type(4)));

static __device__ __forceinline__ unsigned short f2bf(float f) {
    unsigned int u = __float_as_uint(f);
    return (unsigned short)((u + 0x7FFFu + ((u >> 16) & 1u)) >> 16);
}
static __device__ __forceinline__ float bf2f(unsigned short h) {
    return __uint_as_float(((unsigned int)h) << 16);
}
static __device__ __forceinline__ float4 f4zero() { return make_float4(0.f, 0.f, 0.f, 0.f); }

// ---------------- bucketed CSR build ----------------
__global__ void bin_kernel(const int* __restrict__ src, const int* __restrict__ dst,
                           int* __restrict__ bcur, unsigned int* __restrict__ bedge) {
    __shared__ int hist[NBK];
    __shared__ int base[NBK];
    int tid = threadIdx.x;
    for (int i = tid; i < NBK; i += 256) hist[i] = 0;
    __syncthreads();
    int e0 = blockIdx.x * 4096;
    unsigned int pk[16];
    int bk[16], lo[16];
#pragma unroll
    for (int j = 0; j < 16; ++j) {
        int e = e0 + j * 256 + tid;
        bk[j] = -1;
        if (e < NE) {
            int s = src[e], d = dst[e];
            pk[j] = (unsigned int)s | ((unsigned int)d << 16);
            bk[j] = d >> 7;
            lo[j] = atomicAdd(&hist[bk[j]], 1);
        }
    }
    __syncthreads();
    for (int i = tid; i < NBK; i += 256)
        base[i] = hist[i] ? atomicAdd(&bcur[i], hist[i]) : 0;
    __syncthreads();
#pragma unroll
    for (int j = 0; j < 16; ++j) {
        if (bk[j] >= 0) {
            int idx = base[bk[j]] + lo[j];
            if (idx < BCAP) bedge[(size_t)bk[j] * BCAP + idx] = pk[j];
        }
    }
}

__global__ void build_csr_kernel(const unsigned int* __restrict__ bedge,
                                 const int* __restrict__ bcur, int* __restrict__ row_beg,
                                 int* __restrict__ row_end, int* __restrict__ esrc) {
    __shared__ unsigned int se[BCAP];
    __shared__ int h[128], sc[128], cur[128];
    int b = blockIdx.x, tid = threadIdx.x;
    int cnt = min(bcur[b], BCAP);
    for (int i = tid; i < cnt; i += 256) se[i] = bedge[(size_t)b * BCAP + i];
    if (tid < 128) h[tid] = 0;
    __syncthreads();
    for (int i = tid; i < cnt; i += 256) atomicAdd(&h[(se[i] >> 16) & 127], 1);
    __syncthreads();
    if (tid < 128) sc[tid] = h[tid];
    __syncthreads();
    for (int off = 1; off < 128; off <<= 1) {
        int add = 0;
        if (tid < 128 && tid >= off) add = sc[tid - off];
        __syncthreads();
        if (tid < 128) sc[tid] += add;
        __syncthreads();
    }
    if (tid < 128) {
        int ex = sc[tid] - h[tid];
        int n = (b << 7) + tid;
        if (n < NN) {
            row_beg[n] = b * BCAP + ex;
            row_end[n] = b * BCAP + sc[tid];
        }
        cur[tid] = ex;
    }
    __syncthreads();
    for (int i = tid; i < cnt; i += 256) {
        unsigned int v = se[i];
        int dl = (v >> 16) & 127;
        int pos = atomicAdd(&cur[dl], 1);
        esrc[(size_t)b * BCAP + pos] = (int)(v & 0xffffu);
    }
}

// ---------------- weight convert: W[K][128] fp32 -> Wt hi/lo [128][K] bf16 ----------------
__global__ void convert_all(const float* __restrict__ Wres, const float* __restrict__ W1,
                            const float* __restrict__ W2, const float* __restrict__ Ws1,
                            const float* __restrict__ Ws2, short* __restrict__ wresHi,
                            short* __restrict__ wresLo, short* __restrict__ w1Hi,
                            short* __restrict__ w1Lo, short* __restrict__ w2Hi,
                            short* __restrict__ w2Lo, short* __restrict__ ws1Hi,
                            short* __restrict__ ws1Lo, short* __restrict__ ws2Hi,
                            short* __restrict__ ws2Lo) {
    int t = blockIdx.x * 256 + threadIdx.x;
    const float* W;
    short *hi, *lo;
    int K, idx;
    if (t < 8192) { W = Wres; hi = wresHi; lo = wresLo; K = 64; idx = t; }
    else if (t < 16384) { W = W1; hi = w1Hi; lo = w1Lo; K = 64; idx = t - 8192; }
    else if (t < 32768) { W = W2; hi = w2Hi; lo = w2Lo; K = 128; idx = t - 16384; }
    else if (t < 81920) { W = Ws1; hi = ws1Hi; lo = ws1Lo; K = 128; idx = t - 32768; }
    else { W = Ws2; hi = ws2Hi; lo = ws2Lo; K = 128; idx = t - 81920; }
    int m = idx / (K * 128);
    int r = idx - m * K * 128;
    int n = r / K, k = r - n * K;
    float w = W[(size_t)m * K * 128 + k * 128 + n];
    unsigned short hh = f2bf(w);
    hi[idx] = (short)hh;
    lo[idx] = (short)f2bf(w - bf2f(hh));
}

__global__ void to_bf16_kernel(const float* __restrict__ s, short* __restrict__ d, int total) {
    int i = blockIdx.x * 256 + threadIdx.x;
    if (i < total) d[i] = (short)f2bf(s[i]);
}

// ---------------- bf16 gather aggregation, exact fp32 self term ----------------
__global__ void agg128b_kernel(const unsigned int* __restrict__ hb, const float* __restrict__ hf,
                               const int* __restrict__ row_beg, const int* __restrict__ row_end,
                               const int* __restrict__ es, float* __restrict__ t) {
    int wv = threadIdx.x >> 6, lane = threadIdx.x & 63;
    int n = blockIdx.x * 4 + wv;
    if (n >= NN) return;
    int beg = row_beg[n], end = row_end[n];
    float2 acc = ((const float2*)hf)[(size_t)n * 64 + lane];
    int e = beg;
    for (; e + 8 <= end; e += 8) {
        unsigned int v0 = hb[(size_t)es[e] * 64 + lane];
        unsigned int v1 = hb[(size_t)es[e + 1] * 64 + lane];
        unsigned int v2 = hb[(size_t)es[e + 2] * 64 + lane];
        unsigned int v3 = hb[(size_t)es[e + 3] * 64 + lane];
        unsigned int v4 = hb[(size_t)es[e + 4] * 64 + lane];
        unsigned int v5 = hb[(size_t)es[e + 5] * 64 + lane];
        unsigned int v6 = hb[(size_t)es[e + 6] * 64 + lane];
        unsigned int v7 = hb[(size_t)es[e + 7] * 64 + lane];
        acc.x += __uint_as_float(v0 << 16) + __uint_as_float(v1 << 16) +
                 __uint_as_float(v2 << 16) + __uint_as_float(v3 << 16) +
                 __uint_as_float(v4 << 16) + __uint_as_float(v5 << 16) +
                 __uint_as_float(v6 << 16) + __uint_as_float(v7 << 16);
        acc.y += __uint_as_float(v0 & 0xffff0000u) + __uint_as_float(v1 & 0xffff0000u) +
                 __uint_as_float(v2 & 0xffff0000u) + __uint_as_float(v3 & 0xffff0000u) +
                 __uint_as_float(v4 & 0xffff0000u) + __uint_as_float(v5 & 0xffff0000u) +
                 __uint_as_float(v6 & 0xffff0000u) + __uint_as_float(v7 & 0xffff0000u);
    }
    for (; e + 4 <= end; e += 4) {
        unsigned int v0 = hb[(size_t)es[e] * 64 + lane];
        unsigned int v1 = hb[(size_t)es[e + 1] * 64 + lane];
        unsigned int v2 = hb[(size_t)es[e + 2] * 64 + lane];
        unsigned int v3 = hb[(size_t)es[e + 3] * 64 + lane];
        acc.x += __uint_as_float(v0 << 16) + __uint_as_float(v1 << 16) +
                 __uint_as_float(v2 << 16) + __uint_as_float(v3 << 16);
        acc.y += __uint_as_float(v0 & 0xffff0000u) + __uint_as_float(v1 & 0xffff0000u) +
                 __uint_as_float(v2 & 0xffff0000u) + __uint_as_float(v3 & 0xffff0000u);
    }
    for (; e < end; ++e) {
        unsigned int v = hb[(size_t)es[e] * 64 + lane];
        acc.x += __uint_as_float(v << 16);
        acc.y += __uint_as_float(v & 0xffff0000u);
    }
    ((float2*)t)[(size_t)n * 64 + lane] = acc;
}

__global__ void agg64b_kernel(const unsigned short* __restrict__ xb, const float* __restrict__ xf,
                              const int* __restrict__ row_beg, const int* __restrict__ row_end,
                              const int* __restrict__ es, float* __restrict__ t) {
    int wv = threadIdx.x >> 6, lane = threadIdx.x & 63;
    int n = blockIdx.x * 4 + wv;
    if (n >= NN) return;
    int beg = row_beg[n], end = row_end[n];
    float acc = xf[(size_t)n * 64 + lane];
    int e = beg;
    for (; e + 4 <= end; e += 4) {
        int s0 = es[e], s1 = es[e + 1], s2 = es[e + 2], s3 = es[e + 3];
        acc += bf2f(xb[(size_t)s0 * 64 + lane]) + bf2f(xb[(size_t)s1 * 64 + lane]) +
               bf2f(xb[(size_t)s2 * 64 + lane]) + bf2f(xb[(size_t)s3 * 64 + lane]);
    }
    for (; e < end; ++e) acc += bf2f(xb[(size_t)es[e] * 64 + lane]);
    t[(size_t)n * 64 + lane] = acc;
}

// ---------------- fused2: K=128 GIN layer, phase-resident weights, 4 blocks/CU ------------
// h = relu( relu(t@W1+b1)@W2 + b2 + res ). Wave wv owns cols wv*32..wv*32+31 across all 64
// rows. W1 frags resident during GEMM1; same regs reloaded with W2. Residual prefetched into
// registers BEFORE GEMM2 so its HBM latency hides under the MFMA stream.
__global__ __launch_bounds__(256, 4) void fused2(
    const float* __restrict__ tin, const float* __restrict__ xres,
    const short* __restrict__ W1Hi, const short* __restrict__ W1Lo,
    const float* __restrict__ b1, const short* __restrict__ W2Hi,
    const short* __restrict__ W2Lo, const float* __restrict__ b2,
    float* __restrict__ hout, short* __restrict__ hbout) {
    __shared__ short lds[16384];  // hi @ [0..8191], lo @ [8192..16383]
    int tid = threadIdx.x;
    int rowBase = blockIdx.x * 64;
    int lane = tid & 63, wv = tid >> 6;
    int m = lane & 15, g = lane >> 4;

    float4 sv[8];
#pragma unroll
    for (int j = 0; j < 8; ++j) {
        int i = j * 256 + tid;
        int r = i >> 5, c4 = i & 31;
        int row = rowBase + r;
        sv[j] = f4zero();
        if (row < NN) sv[j] = ((const float4*)(tin + (size_t)row * 128))[c4];
    }
    bf16x8 wh[2][4], wl[2][4];
#pragma unroll
    for (int ctl = 0; ctl < 2; ++ctl) {
        int col = wv * 32 + ctl * 16 + m;
#pragma unroll
        for (int kc = 0; kc < 4; ++kc) {
            wh[ctl][kc] = *(const bf16x8*)(W1Hi + col * 128 + kc * 32 + g * 8);
            wl[ctl][kc] = *(const bf16x8*)(W1Lo + col * 128 + kc * 32 + g * 8);
        }
    }
#pragma unroll
    for (int j = 0; j < 8; ++j) {
        int i = j * 256 + tid;
        int r = i >> 5, c4 = i & 31;
        float4 v = sv[j];
        unsigned short hx = f2bf(v.x), hy = f2bf(v.y), hz = f2bf(v.z), hw = f2bf(v.w);
        short4 hv = {(short)hx, (short)hy, (short)hz, (short)hw};
        short4 lv = {(short)f2bf(v.x - bf2f(hx)), (short)f2bf(v.y - bf2f(hy)),
                     (short)f2bf(v.z - bf2f(hz)), (short)f2bf(v.w - bf2f(hw))};
        int sidx = (r * 128 + c4 * 4) ^ ((r & 7) << 3);
        *(short4*)(lds + sidx) = hv;
        *(short4*)(lds + 8192 + sidx) = lv;
    }
    __syncthreads();

    f32x4 acc1[4][2];
#pragma unroll
    for (int s = 0; s < 4; ++s) {
        int rloc = s * 16 + m;
        bf16x8 tHi[4], tLo[4];
#pragma unroll
        for (int kc = 0; kc < 4; ++kc) {
            int idx = (rloc * 128 + kc * 32 + g * 8) ^ ((rloc & 7) << 3);
            tHi[kc] = *(const bf16x8*)(lds + idx);
            tLo[kc] = *(const bf16x8*)(lds + 8192 + idx);
        }
#pragma unroll
        for (int ctl = 0; ctl < 2; ++ctl) {
            float bv = b1[wv * 32 + ctl * 16 + m];
            f32x4 a = {bv, bv, bv, bv};
#pragma unroll
            for (int kc = 0; kc < 4; ++kc) {
                a = __builtin_amdgcn_mfma_f32_16x16x32_bf16(tHi[kc], wh[ctl][kc], a, 0, 0, 0);
                a = __builtin_amdgcn_mfma_f32_16x16x32_bf16(tLo[kc], wh[ctl][kc], a, 0, 0, 0);
                a = __builtin_amdgcn_mfma_f32_16x16x32_bf16(tHi[kc], wl[ctl][kc], a, 0, 0, 0);
            }
            acc1[s][ctl] = a;
        }
    }
    __syncthreads();

#pragma unroll
    for (int s = 0; s < 4; ++s) {
#pragma unroll
        for (int ctl = 0; ctl < 2; ++ctl) {
            int col = wv * 32 + ctl * 16 + m;
#pragma unroll
            for (int i = 0; i < 4; ++i) {
                float u = fmaxf(acc1[s][ctl][i], 0.f);
                unsigned short uh = f2bf(u);
                int ru = s * 16 + g * 4 + i;
                int sidx = (ru * 128 + col) ^ ((ru & 7) << 3);
                lds[sidx] = (short)uh;
                lds[8192 + sidx] = (short)f2bf(u - bf2f(uh));
            }
        }
    }
#pragma unroll
    for (int ctl = 0; ctl < 2; ++ctl) {
        int col = wv * 32 + ctl * 16 + m;
#pragma unroll
        for (int kc = 0; kc < 4; ++kc) {
            wh[ctl][kc] = *(const bf16x8*)(W2Hi + col * 128 + kc * 32 + g * 8);
            wl[ctl][kc] = *(const bf16x8*)(W2Lo + col * 128 + kc * 32 + g * 8);
        }
    }
    __syncthreads();

    // prefetch residual into registers (independent of u) -- hides under GEMM2
    float resv[4][2][4];
#pragma unroll
    for (int s = 0; s < 4; ++s)
#pragma unroll
        for (int ctl = 0; ctl < 2; ++ctl) {
            int col = wv * 32 + ctl * 16 + m;
#pragma unroll
            for (int i = 0; i < 4; ++i) {
                int row = rowBase + s * 16 + g * 4 + i;
                resv[s][ctl][i] = (row < NN) ? xres[(size_t)row * 128 + col] : 0.f;
            }
        }

#pragma unroll
    for (int s = 0; s < 4; ++s) {
        int rloc = s * 16 + m;
        bf16x8 uHi[4], uLo[4];
#pragma unroll
        for (int kc = 0; kc < 4; ++kc) {
            int idx = (rloc * 128 + kc * 32 + g * 8) ^ ((rloc & 7) << 3);
            uHi[kc] = *(const bf16x8*)(lds + idx);
            uLo[kc] = *(const bf16x8*)(lds + 8192 + idx);
        }
#pragma unroll
        for (int ctl = 0; ctl < 2; ++ctl) {
            int col = wv * 32 + ctl * 16 + m;
            float bv = b2[col];
            f32x4 a = {bv, bv, bv, bv};
#pragma unroll
            for (int kc = 0; kc < 4; ++kc) {
                a = __builtin_amdgcn_mfma_f32_16x16x32_bf16(uHi[kc], wh[ctl][kc], a, 0, 0, 0);
                a = __builtin_amdgcn_mfma_f32_16x16x32_bf16(uLo[kc], wh[ctl][kc], a, 0, 0, 0);
                a = __builtin_amdgcn_mfma_f32_16x16x32_bf16(uHi[kc], wl[ctl][kc], a, 0, 0, 0);
            }
#pragma unroll
            for (int i = 0; i < 4; ++i) {
                int row = rowBase + s * 16 + g * 4 + i;
                if (row < NN) {
                    float v = fmaxf(a[i] + resv[s][ctl][i], 0.f);
                    hout[(size_t)row * 128 + col] = v;
                    hbout[(size_t)row * 128 + col] = (short)f2bf(v);
                }
            }
        }
    }
}

// ---------------- fused0: layer 0 (K=64 + in-register Wres residual) ----------------
__global__ __launch_bounds__(256, 4) void fused0(
    const float* __restrict__ tin, const float* __restrict__ x,
    const short* __restrict__ W1Hi, const short* __restrict__ W1Lo,
    const float* __restrict__ b1, const short* __restrict__ W2Hi,
    const short* __restrict__ W2Lo, const float* __restrict__ b2,
    const short* __restrict__ WrHi, const short* __restrict__ WrLo,
    float* __restrict__ hout, short* __restrict__ hbout) {
    __shared__ short lds[16384];  // ph1: tHi@0 tLo@4096 xHi@8192 xLo@12288; ph2: uHi@0 uLo@8192
    int tid = threadIdx.x;
    int rowBase = blockIdx.x * 64;
    int lane = tid & 63, wv = tid >> 6;
    int m = lane & 15, g = lane >> 4;

    float4 sv[4], sx[4];
#pragma unroll
    for (int j = 0; j < 4; ++j) {
        int i = j * 256 + tid;
        int r = i >> 4, c4 = i & 15;
        int row = rowBase + r;
        sv[j] = f4zero();
        sx[j] = f4zero();
        if (row < NN) {
            sv[j] = ((const float4*)(tin + (size_t)row * 64))[c4];
            sx[j] = ((const float4*)(x + (size_t)row * 64))[c4];
        }
    }
    bf16x8 wh[2][4], wl[2][4];
#pragma unroll
    for (int ctl = 0; ctl < 2; ++ctl) {
        int col = wv * 32 + ctl * 16 + m;
#pragma unroll
        for (int kc = 0; kc < 2; ++kc) {
            wh[ctl][kc] = *(const bf16x8*)(W1Hi + col * 64 + kc * 32 + g * 8);
            wl[ctl][kc] = *(const bf16x8*)(W1Lo + col * 64 + kc * 32 + g * 8);
            wh[ctl][2 + kc] = *(const bf16x8*)(WrHi + col * 64 + kc * 32 + g * 8);
            wl[ctl][2 + kc] = *(const bf16x8*)(WrLo + col * 64 + kc * 32 + g * 8);
        }
    }
#pragma unroll
    for (int j = 0; j < 4; ++j) {
        int i = j * 256 + tid;
        int r = i >> 4, c4 = i & 15;
        int sidx = (r * 64 + c4 * 4) ^ ((r & 7) << 3);
        float4 v = sv[j];
        unsigned short hx = f2bf(v.x), hy = f2bf(v.y), hz = f2bf(v.z), hw = f2bf(v.w);
        short4 hv = {(short)hx, (short)hy, (short)hz, (short)hw};
        short4 lv = {(short)f2bf(v.x - bf2f(hx)), (short)f2bf(v.y - bf2f(hy)),
                     (short)f2bf(v.z - bf2f(hz)), (short)f2bf(v.w - bf2f(hw))};
        *(short4*)(lds + sidx) = hv;
        *(short4*)(lds + 4096 + sidx) = lv;
        v = sx[j];
        hx = f2bf(v.x), hy = f2bf(v.y), hz = f2bf(v.z), hw = f2bf(v.w);
        short4 hv2 = {(short)hx, (short)hy, (short)hz, (short)hw};
        short4 lv2 = {(short)f2bf(v.x - bf2f(hx)), (short)f2bf(v.y - bf2f(hy)),
                      (short)f2bf(v.z - bf2f(hz)), (short)f2bf(v.w - bf2f(hw))};
        *(short4*)(lds + 8192 + sidx) = hv2;
        *(short4*)(lds + 12288 + sidx) = lv2;
    }
    __syncthreads();

    f32x4 acc1[4][2], racc[4][2];
#pragma unroll
    for (int s = 0; s < 4; ++s) {
        int rloc = s * 16 + m;
        bf16x8 tH[2], tL[2], xH[2], xL[2];
#pragma unroll
        for (int kc = 0; kc < 2; ++kc) {
            int idx = (rloc * 64 + kc * 32 + g * 8) ^ ((rloc & 7) << 3);
            tH[kc] = *(const bf16x8*)(lds + idx);
            tL[kc] = *(const bf16x8*)(lds + 4096 + idx);
            xH[kc] = *(const bf16x8*)(lds + 8192 + idx);
            xL[kc] = *(const bf16x8*)(lds + 12288 + idx);
        }
#pragma unroll
        for (int ctl = 0; ctl < 2; ++ctl) {
            float bv = b1[wv * 32 + ctl * 16 + m];
            f32x4 a = {bv, bv, bv, bv};
            f32x4 r4 = {0.f, 0.f, 0.f, 0.f};
#pragma unroll
            for (int kc = 0; kc < 2; ++kc) {
                a = __builtin_amdgcn_mfma_f32_16x16x32_bf16(tH[kc], wh[ctl][kc], a, 0, 0, 0);
                a = __builtin_amdgcn_mfma_f32_16x16x32_bf16(tL[kc], wh[ctl][kc], a, 0, 0, 0);
                a = __builtin_amdgcn_mfma_f32_16x16x32_bf16(tH[kc], wl[ctl][kc], a, 0, 0, 0);
                r4 = __builtin_amdgcn_mfma_f32_16x16x32_bf16(xH[kc], wh[ctl][2 + kc], r4, 0, 0, 0);
                r4 = __builtin_amdgcn_mfma_f32_16x16x32_bf16(xL[kc], wh[ctl][2 + kc], r4, 0, 0, 0);
                r4 = __builtin_amdgcn_mfma_f32_16x16x32_bf16(xH[kc], wl[ctl][2 + kc], r4, 0, 0, 0);
            }
            acc1[s][ctl] = a;
            racc[s][ctl] = r4;
        }
    }
    __syncthreads();

#pragma unroll
    for (int s = 0; s < 4; ++s) {
#pragma unroll
        for (int ctl = 0; ctl < 2; ++ctl) {
            int col = wv * 32 + ctl * 16 + m;
#pragma unroll
            for (int i = 0; i < 4; ++i) {
                float u = fmaxf(acc1[s][ctl][i], 0.f);
                unsigned short uh = f2bf(u);
                int ru = s * 16 + g * 4 + i;
                int sidx = (ru * 128 + col) ^ ((ru & 7) << 3);
                lds[sidx] = (short)uh;
                lds[8192 + sidx] = (short)f2bf(u - bf2f(uh));
            }
        }
    }
#pragma unroll
    for (int ctl = 0; ctl < 2; ++ctl) {
        int col = wv * 32 + ctl * 16 + m;
#pragma unroll
        for (int kc = 0; kc < 4; ++kc) {
            wh[ctl][kc] = *(const bf16x8*)(W2Hi + col * 128 + kc * 32 + g * 8);
            wl[ctl][kc] = *(const bf16x8*)(W2Lo + col * 128 + kc * 32 + g * 8);
        }
    }
    __syncthreads();

#pragma unroll
    for (int s = 0; s < 4; ++s) {
        int rloc = s * 16 + m;
        bf16x8 uHi[4], uLo[4];
#pragma unroll
        for (int kc = 0; kc < 4; ++kc) {
            int idx = (rloc * 128 + kc * 32 + g * 8) ^ ((rloc & 7) << 3);
            uHi[kc] = *(const bf16x8*)(lds + idx);
            uLo[kc] = *(const bf16x8*)(lds + 8192 + idx);
        }
#pragma unroll
        for (int ctl = 0; ctl < 2; ++ctl) {
            int col = wv * 32 + ctl * 16 + m;
            float bv = b2[col];
            f32x4 a = {bv, bv, bv, bv};
#pragma unroll
            for (int kc = 0; kc < 4; ++kc) {
                a = __builtin_amdgcn_mfma_f32_16x16x32_bf16(uHi[kc], wh[ctl][kc], a, 0, 0, 0);
                a = __builtin_amdgcn_mfma_f32_16x16x32_bf16(uLo[kc], wh[ctl][kc], a, 0, 0, 0);
                a = __builtin_amdgcn_mfma_f32_16x16x32_bf16(uHi[kc], wl[ctl][kc], a, 0, 0, 0);
            }
#pragma unroll
            for (int i = 0; i < 4; ++i) {
                int row = rowBase + s * 16 + g * 4 + i;
                if (row < NN) {
                    float v = fmaxf(a[i] + racc[s][ctl][i], 0.f);
                    hout[(size_t)row * 128 + col] = v;
                    hbout[(size_t)row * 128 + col] = (short)f2bf(v);
                }
            }
        }
    }
}

// ---------------- fused mean-pool + FC head ----------------
static __device__ __forceinline__ int lbound(const int* __restrict__ a, int n, int v) {
    int lo = 0, hi = n;
    while (lo < hi) {
        int mid = (lo + hi) >> 1;
        if (a[mid] < v) lo = mid + 1;
        else hi = mid;
    }
    return lo;
}

__global__ void head_kernel(const float* __restrict__ h, const int* __restrict__ batch,
                            const float* __restrict__ fW1, const float* __restrict__ fb1,
                            const float* __restrict__ fW2, const float* __restrict__ fb2,
                            float* __restrict__ out) {
    __shared__ float sp[128];
    __shared__ float su[128];
    __shared__ int sr[2];
    int g = blockIdx.x, t = threadIdx.x;
    if (t == 0) sr[0] = lbound(batch, NN, g);
    if (t == 1) sr[1] = lbound(batch, NN, g + 1);
    __syncthreads();
    int beg = sr[0], end = sr[1];
    float acc = 0.f;
    for (int i = beg; i < end; ++i) acc += h[(size_t)i * 128 + t];
    sp[t] = acc / (float)max(end - beg, 1);
    __syncthreads();
    float a = fb1[t];
#pragma unroll 4
    for (int k = 0; k < 128; ++k) a = fmaf(sp[k], fW1[k * 128 + t], a);
    a = a > 0.f ? a : 0.01f * a;
    su[t] = a * fW2[t];
    __syncthreads();
    for (int s2 = 64; s2 > 0; s2 >>= 1) {
        if (t < s2) su[t] += su[t + s2];
        __syncthreads();
    }
    if (t == 0) out[g] = su[0] + fb2[0];
}

extern "C" void kernel_launch(void* const* d_in, const int* in_sizes, int n_in,
                              void* d_out, int out_size, void* d_ws, size_t ws_size,
                              hipStream_t stream) {
    const float* x = (const float*)d_in[0];
    const int* eidx = (const int*)d_in[1];
    const int* src = eidx;
    const int* dst = eidx + NE;
    const int* batch = (const int*)d_in[2];
    const float* l0_W1 = (const float*)d_in[3];
    const float* l0_b1 = (const float*)d_in[4];
    const float* l0_W2 = (const float*)d_in[5];
    const float* l0_b2 = (const float*)d_in[6];
    const float* l0_Wres = (const float*)d_in[7];
    const float* Ws1 = (const float*)d_in[8];
    const float* bs1 = (const float*)d_in[9];
    const float* Ws2 = (const float*)d_in[10];
    const float* bs2 = (const float*)d_in[11];
    const float* fW1 = (const float*)d_in[12];
    const float* fb1 = (const float*)d_in[13];
    const float* fW2 = (const float*)d_in[14];
    const float* fb2 = (const float*)d_in[15];
    float* out = (float*)d_out;

    size_t used = 0;
    auto alloc = [&](size_t bytes) -> char* {
        char* r = (char*)d_ws + used;
        used = (used + bytes + 255) & ~(size_t)255;
        return r;
    };
    float* A = (float*)alloc((size_t)NN * HID * 4);  // t buffer
    float* B = (float*)alloc((size_t)NN * HID * 4);  // h ping
    float* C = (float*)alloc((size_t)NN * HID * 4);  // h pong
    int* bcur = (int*)alloc((size_t)NBK * 4);
    int* row_beg = (int*)alloc((size_t)NN * 4);
    int* row_end = (int*)alloc((size_t)NN * 4);
    int* esrc = (int*)alloc((size_t)NBK * BCAP * 4);
    // bedge (4.0MB) aliases xb (6.4MB): bedge dead after build_csr
    char* shared_region = alloc((size_t)NN * IND * 2 > (size_t)NBK * BCAP * 4
                                    ? (size_t)NN * IND * 2
                                    : (size_t)NBK * BCAP * 4);
    unsigned int* bedge = (unsigned int*)shared_region;
    short* xb = (short*)shared_region;
    short* wresHi = (short*)alloc(128 * 64 * 2);
    short* wresLo = (short*)alloc(128 * 64 * 2);
    short* w1Hi = (short*)alloc(128 * 64 * 2);
    short* w1Lo = (short*)alloc(128 * 64 * 2);
    short* w2Hi = (short*)alloc(128 * 128 * 2);
    short* w2Lo = (short*)alloc(128 * 128 * 2);
    short* ws1Hi = (short*)alloc(3 * 128 * 128 * 2);
    short* ws1Lo = (short*)alloc(3 * 128 * 128 * 2);
    short* ws2Hi = (short*)alloc(3 * 128 * 128 * 2);
    short* ws2Lo = (short*)alloc(3 * 128 * 128 * 2);
    short* hb = (short*)alloc((size_t)NN * HID * 2);

    hipMemsetAsync(bcur, 0, (size_t)NBK * 4, stream);

    const int GB = (NN + 63) / 64;   // 782
    const int AGGB = (NN + 3) / 4;   // 12500

    convert_all<<<512, 256, 0, stream>>>(l0_Wres, l0_W1, l0_W2, Ws1, Ws2, wresHi, wresLo, w1Hi,
                                         w1Lo, w2Hi, w2Lo, ws1Hi, ws1Lo, ws2Hi, ws2Lo);

    bin_kernel<<<(NE + 4095) / 4096, 256, 0, stream>>>(src, dst, bcur, bedge);
    build_csr_kernel<<<NBK, 256, 0, stream>>>(bedge, bcur, row_beg, row_end, esrc);

    to_bf16_kernel<<<(NN * IND + 255) / 256, 256, 0, stream>>>(x, xb, NN * IND);

    // layer 0: t0 = x + agg(x) -> A; h0 = fused0(A, x) -> B (+ hb)
    agg64b_kernel<<<AGGB, 256, 0, stream>>>((const unsigned short*)xb, x, row_beg, row_end, esrc,
                                            A);
    fused0<<<GB, 256, 0, stream>>>(A, x, w1Hi, w1Lo, l0_b1, w2Hi, w2Lo, l0_b2, wresHi, wresLo, B,
                                   hb);

    // layers 1..3: t = h + agg(hb) -> A; h' = fused2(A, h) -> ping-pong (+ hb)
    float* hcur = B;
    float* hnxt = C;
    for (int l = 0; l < 3; ++l) {
        agg128b_kernel<<<AGGB, 256, 0, stream>>>((const unsigned int*)hb, hcur, row_beg, row_end,
                                                 esrc, A);
        fused2<<<GB, 256, 0, stream>>>(A, hcur, ws1Hi + (size_t)l * 16384,
                                       ws1Lo + (size_t)l * 16384, bs1 + (size_t)l * HID,
                                       ws2Hi + (size_t)l * 16384, ws2Lo + (size_t)l * 16384,
                                       bs2 + (size_t)l * HID, hnxt, hb);
        float* t2 = hcur;
        hcur = hnxt;
        hnxt = t2;
    }

    head_kernel<<<NG, 128, 0, stream>>>(hcur, batch, fW1, fb1, fW2, fb2, out);
}

// Round 12
// 422.438 us; speedup vs baseline: 1.2046x; 1.2046x over previous
//
#include <hip/hip_runtime.h>

#define NN 50000
#define NE 800000
#define IND 64
#define HID 128
#define NG 1024

#define NBK 391   // buckets of 128 dst nodes
#define BCAP 2560 // padded capacity per bucket (avg 2046, +11 sigma)

typedef short bf16x8 __attribute__((ext_vector_type(8)));
typedef float f32x4 __attribute__((ext_vector_type(4)));

static __device__ __forceinline__ unsigned short f2bf(float f) {
    unsigned int u = __float_as_uint(f);
    return (unsigned short)((u + 0x7FFFu + ((u >> 16) & 1u)) >> 16);
}
static __device__ __forceinline__ float bf2f(unsigned short h) {
    return __uint_as_float(((unsigned int)h) << 16);
}
static __device__ __forceinline__ float4 f4zero() { return make_float4(0.f, 0.f, 0.f, 0.f); }

// ---------------- bucketed CSR build ----------------
__global__ void bin_kernel(const int* __restrict__ src, const int* __restrict__ dst,
                           int* __restrict__ bcur, unsigned int* __restrict__ bedge) {
    __shared__ int hist[NBK];
    __shared__ int base[NBK];
    int tid = threadIdx.x;
    for (int i = tid; i < NBK; i += 256) hist[i] = 0;
    __syncthreads();
    int e0 = blockIdx.x * 4096;
    unsigned int pk[16];
    int bk[16], lo[16];
#pragma unroll
    for (int j = 0; j < 16; ++j) {
        int e = e0 + j * 256 + tid;
        bk[j] = -1;
        if (e < NE) {
            int s = src[e], d = dst[e];
            pk[j] = (unsigned int)s | ((unsigned int)d << 16);
            bk[j] = d >> 7;
            lo[j] = atomicAdd(&hist[bk[j]], 1);
        }
    }
    __syncthreads();
    for (int i = tid; i < NBK; i += 256)
        base[i] = hist[i] ? atomicAdd(&bcur[i], hist[i]) : 0;
    __syncthreads();
#pragma unroll
    for (int j = 0; j < 16; ++j) {
        if (bk[j] >= 0) {
            int idx = base[bk[j]] + lo[j];
            if (idx < BCAP) bedge[(size_t)bk[j] * BCAP + idx] = pk[j];
        }
    }
}

__global__ void build_csr_kernel(const unsigned int* __restrict__ bedge,
                                 const int* __restrict__ bcur, int* __restrict__ row_beg,
                                 int* __restrict__ row_end, int* __restrict__ esrc) {
    __shared__ unsigned int se[BCAP];
    __shared__ int h[128], sc[128], cur[128];
    int b = blockIdx.x, tid = threadIdx.x;
    int cnt = min(bcur[b], BCAP);
    for (int i = tid; i < cnt; i += 256) se[i] = bedge[(size_t)b * BCAP + i];
    if (tid < 128) h[tid] = 0;
    __syncthreads();
    for (int i = tid; i < cnt; i += 256) atomicAdd(&h[(se[i] >> 16) & 127], 1);
    __syncthreads();
    if (tid < 128) sc[tid] = h[tid];
    __syncthreads();
    for (int off = 1; off < 128; off <<= 1) {
        int add = 0;
        if (tid < 128 && tid >= off) add = sc[tid - off];
        __syncthreads();
        if (tid < 128) sc[tid] += add;
        __syncthreads();
    }
    if (tid < 128) {
        int ex = sc[tid] - h[tid];
        int n = (b << 7) + tid;
        if (n < NN) {
            row_beg[n] = b * BCAP + ex;
            row_end[n] = b * BCAP + sc[tid];
        }
        cur[tid] = ex;
    }
    __syncthreads();
    for (int i = tid; i < cnt; i += 256) {
        unsigned int v = se[i];
        int dl = (v >> 16) & 127;
        int pos = atomicAdd(&cur[dl], 1);
        esrc[(size_t)b * BCAP + pos] = (int)(v & 0xffffu);
    }
}

// ---------------- weight convert: W[K][128] fp32 -> Wt hi/lo [128][K] bf16 ----------------
__global__ void convert_all(const float* __restrict__ Wres, const float* __restrict__ W1,
                            const float* __restrict__ W2, const float* __restrict__ Ws1,
                            const float* __restrict__ Ws2, short* __restrict__ wresHi,
                            short* __restrict__ wresLo, short* __restrict__ w1Hi,
                            short* __restrict__ w1Lo, short* __restrict__ w2Hi,
                            short* __restrict__ w2Lo, short* __restrict__ ws1Hi,
                            short* __restrict__ ws1Lo, short* __restrict__ ws2Hi,
                            short* __restrict__ ws2Lo) {
    int t = blockIdx.x * 256 + threadIdx.x;
    const float* W;
    short *hi, *lo;
    int K, idx;
    if (t < 8192) { W = Wres; hi = wresHi; lo = wresLo; K = 64; idx = t; }
    else if (t < 16384) { W = W1; hi = w1Hi; lo = w1Lo; K = 64; idx = t - 8192; }
    else if (t < 32768) { W = W2; hi = w2Hi; lo = w2Lo; K = 128; idx = t - 16384; }
    else if (t < 81920) { W = Ws1; hi = ws1Hi; lo = ws1Lo; K = 128; idx = t - 32768; }
    else { W = Ws2; hi = ws2Hi; lo = ws2Lo; K = 128; idx = t - 81920; }
    int m = idx / (K * 128);
    int r = idx - m * K * 128;
    int n = r / K, k = r - n * K;
    float w = W[(size_t)m * K * 128 + k * 128 + n];
    unsigned short hh = f2bf(w);
    hi[idx] = (short)hh;
    lo[idx] = (short)f2bf(w - bf2f(hh));
}

__global__ void to_bf16_kernel(const float* __restrict__ s, short* __restrict__ d, int total) {
    int i = blockIdx.x * 256 + threadIdx.x;
    if (i < total) d[i] = (short)f2bf(s[i]);
}

// ---------------- bf16 gather aggregation, exact fp32 self term ----------------
__global__ void agg128b_kernel(const unsigned int* __restrict__ hb, const float* __restrict__ hf,
                               const int* __restrict__ row_beg, const int* __restrict__ row_end,
                               const int* __restrict__ es, float* __restrict__ t) {
    int wv = threadIdx.x >> 6, lane = threadIdx.x & 63;
    int n = blockIdx.x * 4 + wv;
    if (n >= NN) return;
    int beg = row_beg[n], end = row_end[n];
    float2 acc = ((const float2*)hf)[(size_t)n * 64 + lane];
    int e = beg;
    for (; e + 8 <= end; e += 8) {
        unsigned int v0 = hb[(size_t)es[e] * 64 + lane];
        unsigned int v1 = hb[(size_t)es[e + 1] * 64 + lane];
        unsigned int v2 = hb[(size_t)es[e + 2] * 64 + lane];
        unsigned int v3 = hb[(size_t)es[e + 3] * 64 + lane];
        unsigned int v4 = hb[(size_t)es[e + 4] * 64 + lane];
        unsigned int v5 = hb[(size_t)es[e + 5] * 64 + lane];
        unsigned int v6 = hb[(size_t)es[e + 6] * 64 + lane];
        unsigned int v7 = hb[(size_t)es[e + 7] * 64 + lane];
        acc.x += __uint_as_float(v0 << 16) + __uint_as_float(v1 << 16) +
                 __uint_as_float(v2 << 16) + __uint_as_float(v3 << 16) +
                 __uint_as_float(v4 << 16) + __uint_as_float(v5 << 16) +
                 __uint_as_float(v6 << 16) + __uint_as_float(v7 << 16);
        acc.y += __uint_as_float(v0 & 0xffff0000u) + __uint_as_float(v1 & 0xffff0000u) +
                 __uint_as_float(v2 & 0xffff0000u) + __uint_as_float(v3 & 0xffff0000u) +
                 __uint_as_float(v4 & 0xffff0000u) + __uint_as_float(v5 & 0xffff0000u) +
                 __uint_as_float(v6 & 0xffff0000u) + __uint_as_float(v7 & 0xffff0000u);
    }
    for (; e + 4 <= end; e += 4) {
        unsigned int v0 = hb[(size_t)es[e] * 64 + lane];
        unsigned int v1 = hb[(size_t)es[e + 1] * 64 + lane];
        unsigned int v2 = hb[(size_t)es[e + 2] * 64 + lane];
        unsigned int v3 = hb[(size_t)es[e + 3] * 64 + lane];
        acc.x += __uint_as_float(v0 << 16) + __uint_as_float(v1 << 16) +
                 __uint_as_float(v2 << 16) + __uint_as_float(v3 << 16);
        acc.y += __uint_as_float(v0 & 0xffff0000u) + __uint_as_float(v1 & 0xffff0000u) +
                 __uint_as_float(v2 & 0xffff0000u) + __uint_as_float(v3 & 0xffff0000u);
    }
    for (; e < end; ++e) {
        unsigned int v = hb[(size_t)es[e] * 64 + lane];
        acc.x += __uint_as_float(v << 16);
        acc.y += __uint_as_float(v & 0xffff0000u);
    }
    ((float2*)t)[(size_t)n * 64 + lane] = acc;
}

__global__ void agg64b_kernel(const unsigned short* __restrict__ xb, const float* __restrict__ xf,
                              const int* __restrict__ row_beg, const int* __restrict__ row_end,
                              const int* __restrict__ es, float* __restrict__ t) {
    int wv = threadIdx.x >> 6, lane = threadIdx.x & 63;
    int n = blockIdx.x * 4 + wv;
    if (n >= NN) return;
    int beg = row_beg[n], end = row_end[n];
    float acc = xf[(size_t)n * 64 + lane];
    int e = beg;
    for (; e + 4 <= end; e += 4) {
        int s0 = es[e], s1 = es[e + 1], s2 = es[e + 2], s3 = es[e + 3];
        acc += bf2f(xb[(size_t)s0 * 64 + lane]) + bf2f(xb[(size_t)s1 * 64 + lane]) +
               bf2f(xb[(size_t)s2 * 64 + lane]) + bf2f(xb[(size_t)s3 * 64 + lane]);
    }
    for (; e < end; ++e) acc += bf2f(xb[(size_t)es[e] * 64 + lane]);
    t[(size_t)n * 64 + lane] = acc;
}

// ---------------- fused2: K=128 GIN layer, phase-resident weights, 4 blocks/CU ------------
// h = relu( relu(t@W1+b1)@W2 + b2 + res ). Wave wv owns cols wv*32..wv*32+31 across all 64
// rows. W1 frags resident during GEMM1; same regs reloaded with W2 for GEMM2.
// NO residual prefetch (round-11 lesson: +32 VGPR at the 128 cap spills to scratch,
// +90MB HBM traffic). Epilogue reads xres inline.
__global__ __launch_bounds__(256, 4) void fused2(
    const float* __restrict__ tin, const float* __restrict__ xres,
    const short* __restrict__ W1Hi, const short* __restrict__ W1Lo,
    const float* __restrict__ b1, const short* __restrict__ W2Hi,
    const short* __restrict__ W2Lo, const float* __restrict__ b2,
    float* __restrict__ hout, short* __restrict__ hbout) {
    __shared__ short lds[16384];  // hi @ [0..8191], lo @ [8192..16383]
    int tid = threadIdx.x;
    int rowBase = blockIdx.x * 64;
    int lane = tid & 63, wv = tid >> 6;
    int m = lane & 15, g = lane >> 4;

    float4 sv[8];
#pragma unroll
    for (int j = 0; j < 8; ++j) {
        int i = j * 256 + tid;
        int r = i >> 5, c4 = i & 31;
        int row = rowBase + r;
        sv[j] = f4zero();
        if (row < NN) sv[j] = ((const float4*)(tin + (size_t)row * 128))[c4];
    }
    bf16x8 wh[2][4], wl[2][4];
#pragma unroll
    for (int ctl = 0; ctl < 2; ++ctl) {
        int col = wv * 32 + ctl * 16 + m;
#pragma unroll
        for (int kc = 0; kc < 4; ++kc) {
            wh[ctl][kc] = *(const bf16x8*)(W1Hi + col * 128 + kc * 32 + g * 8);
            wl[ctl][kc] = *(const bf16x8*)(W1Lo + col * 128 + kc * 32 + g * 8);
        }
    }
#pragma unroll
    for (int j = 0; j < 8; ++j) {
        int i = j * 256 + tid;
        int r = i >> 5, c4 = i & 31;
        float4 v = sv[j];
        unsigned short hx = f2bf(v.x), hy = f2bf(v.y), hz = f2bf(v.z), hw = f2bf(v.w);
        short4 hv = {(short)hx, (short)hy, (short)hz, (short)hw};
        short4 lv = {(short)f2bf(v.x - bf2f(hx)), (short)f2bf(v.y - bf2f(hy)),
                     (short)f2bf(v.z - bf2f(hz)), (short)f2bf(v.w - bf2f(hw))};
        int sidx = (r * 128 + c4 * 4) ^ ((r & 7) << 3);
        *(short4*)(lds + sidx) = hv;
        *(short4*)(lds + 8192 + sidx) = lv;
    }
    __syncthreads();

    f32x4 acc1[4][2];
#pragma unroll
    for (int s = 0; s < 4; ++s) {
        int rloc = s * 16 + m;
        bf16x8 tHi[4], tLo[4];
#pragma unroll
        for (int kc = 0; kc < 4; ++kc) {
            int idx = (rloc * 128 + kc * 32 + g * 8) ^ ((rloc & 7) << 3);
            tHi[kc] = *(const bf16x8*)(lds + idx);
            tLo[kc] = *(const bf16x8*)(lds + 8192 + idx);
        }
#pragma unroll
        for (int ctl = 0; ctl < 2; ++ctl) {
            float bv = b1[wv * 32 + ctl * 16 + m];
            f32x4 a = {bv, bv, bv, bv};
#pragma unroll
            for (int kc = 0; kc < 4; ++kc) {
                a = __builtin_amdgcn_mfma_f32_16x16x32_bf16(tHi[kc], wh[ctl][kc], a, 0, 0, 0);
                a = __builtin_amdgcn_mfma_f32_16x16x32_bf16(tLo[kc], wh[ctl][kc], a, 0, 0, 0);
                a = __builtin_amdgcn_mfma_f32_16x16x32_bf16(tHi[kc], wl[ctl][kc], a, 0, 0, 0);
            }
            acc1[s][ctl] = a;
        }
    }
    __syncthreads();

#pragma unroll
    for (int s = 0; s < 4; ++s) {
#pragma unroll
        for (int ctl = 0; ctl < 2; ++ctl) {
            int col = wv * 32 + ctl * 16 + m;
#pragma unroll
            for (int i = 0; i < 4; ++i) {
                float u = fmaxf(acc1[s][ctl][i], 0.f);
                unsigned short uh = f2bf(u);
                int ru = s * 16 + g * 4 + i;
                int sidx = (ru * 128 + col) ^ ((ru & 7) << 3);
                lds[sidx] = (short)uh;
                lds[8192 + sidx] = (short)f2bf(u - bf2f(uh));
            }
        }
    }
#pragma unroll
    for (int ctl = 0; ctl < 2; ++ctl) {
        int col = wv * 32 + ctl * 16 + m;
#pragma unroll
        for (int kc = 0; kc < 4; ++kc) {
            wh[ctl][kc] = *(const bf16x8*)(W2Hi + col * 128 + kc * 32 + g * 8);
            wl[ctl][kc] = *(const bf16x8*)(W2Lo + col * 128 + kc * 32 + g * 8);
        }
    }
    __syncthreads();

#pragma unroll
    for (int s = 0; s < 4; ++s) {
        int rloc = s * 16 + m;
        bf16x8 uHi[4], uLo[4];
#pragma unroll
        for (int kc = 0; kc < 4; ++kc) {
            int idx = (rloc * 128 + kc * 32 + g * 8) ^ ((rloc & 7) << 3);
            uHi[kc] = *(const bf16x8*)(lds + idx);
            uLo[kc] = *(const bf16x8*)(lds + 8192 + idx);
        }
#pragma unroll
        for (int ctl = 0; ctl < 2; ++ctl) {
            int col = wv * 32 + ctl * 16 + m;
            float bv = b2[col];
            f32x4 a = {bv, bv, bv, bv};
#pragma unroll
            for (int kc = 0; kc < 4; ++kc) {
                a = __builtin_amdgcn_mfma_f32_16x16x32_bf16(uHi[kc], wh[ctl][kc], a, 0, 0, 0);
                a = __builtin_amdgcn_mfma_f32_16x16x32_bf16(uLo[kc], wh[ctl][kc], a, 0, 0, 0);
                a = __builtin_amdgcn_mfma_f32_16x16x32_bf16(uHi[kc], wl[ctl][kc], a, 0, 0, 0);
            }
#pragma unroll
            for (int i = 0; i < 4; ++i) {
                int row = rowBase + s * 16 + g * 4 + i;
                if (row < NN) {
                    float v = fmaxf(a[i] + xres[(size_t)row * 128 + col], 0.f);
                    hout[(size_t)row * 128 + col] = v;
                    hbout[(size_t)row * 128 + col] = (short)f2bf(v);
                }
            }
        }
    }
}

// ---------------- fused0: layer 0 (K=64 + in-register Wres residual), 3 blocks/CU ---------
// racc (+32 VGPR) does not fit the 4-block 128-VGPR cap -- keep bounds 3 (round-10 config).
__global__ __launch_bounds__(256, 3) void fused0(
    const float* __restrict__ tin, const float* __restrict__ x,
    const short* __restrict__ W1Hi, const short* __restrict__ W1Lo,
    const float* __restrict__ b1, const short* __restrict__ W2Hi,
    const short* __restrict__ W2Lo, const float* __restrict__ b2,
    const short* __restrict__ WrHi, const short* __restrict__ WrLo,
    float* __restrict__ hout, short* __restrict__ hbout) {
    __shared__ short lds[16384];  // ph1: tHi@0 tLo@4096 xHi@8192 xLo@12288; ph2: uHi@0 uLo@8192
    int tid = threadIdx.x;
    int rowBase = blockIdx.x * 64;
    int lane = tid & 63, wv = tid >> 6;
    int m = lane & 15, g = lane >> 4;

    float4 sv[4], sx[4];
#pragma unroll
    for (int j = 0; j < 4; ++j) {
        int i = j * 256 + tid;
        int r = i >> 4, c4 = i & 15;
        int row = rowBase + r;
        sv[j] = f4zero();
        sx[j] = f4zero();
        if (row < NN) {
            sv[j] = ((const float4*)(tin + (size_t)row * 64))[c4];
            sx[j] = ((const float4*)(x + (size_t)row * 64))[c4];
        }
    }
    bf16x8 wh[2][4], wl[2][4];
#pragma unroll
    for (int ctl = 0; ctl < 2; ++ctl) {
        int col = wv * 32 + ctl * 16 + m;
#pragma unroll
        for (int kc = 0; kc < 2; ++kc) {
            wh[ctl][kc] = *(const bf16x8*)(W1Hi + col * 64 + kc * 32 + g * 8);
            wl[ctl][kc] = *(const bf16x8*)(W1Lo + col * 64 + kc * 32 + g * 8);
            wh[ctl][2 + kc] = *(const bf16x8*)(WrHi + col * 64 + kc * 32 + g * 8);
            wl[ctl][2 + kc] = *(const bf16x8*)(WrLo + col * 64 + kc * 32 + g * 8);
        }
    }
#pragma unroll
    for (int j = 0; j < 4; ++j) {
        int i = j * 256 + tid;
        int r = i >> 4, c4 = i & 15;
        int sidx = (r * 64 + c4 * 4) ^ ((r & 7) << 3);
        float4 v = sv[j];
        unsigned short hx = f2bf(v.x), hy = f2bf(v.y), hz = f2bf(v.z), hw = f2bf(v.w);
        short4 hv = {(short)hx, (short)hy, (short)hz, (short)hw};
        short4 lv = {(short)f2bf(v.x - bf2f(hx)), (short)f2bf(v.y - bf2f(hy)),
                     (short)f2bf(v.z - bf2f(hz)), (short)f2bf(v.w - bf2f(hw))};
        *(short4*)(lds + sidx) = hv;
        *(short4*)(lds + 4096 + sidx) = lv;
        v = sx[j];
        hx = f2bf(v.x), hy = f2bf(v.y), hz = f2bf(v.z), hw = f2bf(v.w);
        short4 hv2 = {(short)hx, (short)hy, (short)hz, (short)hw};
        short4 lv2 = {(short)f2bf(v.x - bf2f(hx)), (short)f2bf(v.y - bf2f(hy)),
                      (short)f2bf(v.z - bf2f(hz)), (short)f2bf(v.w - bf2f(hw))};
        *(short4*)(lds + 8192 + sidx) = hv2;
        *(short4*)(lds + 12288 + sidx) = lv2;
    }
    __syncthreads();

    f32x4 acc1[4][2], racc[4][2];
#pragma unroll
    for (int s = 0; s < 4; ++s) {
        int rloc = s * 16 + m;
        bf16x8 tH[2], tL[2], xH[2], xL[2];
#pragma unroll
        for (int kc = 0; kc < 2; ++kc) {
            int idx = (rloc * 64 + kc * 32 + g * 8) ^ ((rloc & 7) << 3);
            tH[kc] = *(const bf16x8*)(lds + idx);
            tL[kc] = *(const bf16x8*)(lds + 4096 + idx);
            xH[kc] = *(const bf16x8*)(lds + 8192 + idx);
            xL[kc] = *(const bf16x8*)(lds + 12288 + idx);
        }
#pragma unroll
        for (int ctl = 0; ctl < 2; ++ctl) {
            float bv = b1[wv * 32 + ctl * 16 + m];
            f32x4 a = {bv, bv, bv, bv};
            f32x4 r4 = {0.f, 0.f, 0.f, 0.f};
#pragma unroll
            for (int kc = 0; kc < 2; ++kc) {
                a = __builtin_amdgcn_mfma_f32_16x16x32_bf16(tH[kc], wh[ctl][kc], a, 0, 0, 0);
                a = __builtin_amdgcn_mfma_f32_16x16x32_bf16(tL[kc], wh[ctl][kc], a, 0, 0, 0);
                a = __builtin_amdgcn_mfma_f32_16x16x32_bf16(tH[kc], wl[ctl][kc], a, 0, 0, 0);
                r4 = __builtin_amdgcn_mfma_f32_16x16x32_bf16(xH[kc], wh[ctl][2 + kc], r4, 0, 0, 0);
                r4 = __builtin_amdgcn_mfma_f32_16x16x32_bf16(xL[kc], wh[ctl][2 + kc], r4, 0, 0, 0);
                r4 = __builtin_amdgcn_mfma_f32_16x16x32_bf16(xH[kc], wl[ctl][2 + kc], r4, 0, 0, 0);
            }
            acc1[s][ctl] = a;
            racc[s][ctl] = r4;
        }
    }
    __syncthreads();

#pragma unroll
    for (int s = 0; s < 4; ++s) {
#pragma unroll
        for (int ctl = 0; ctl < 2; ++ctl) {
            int col = wv * 32 + ctl * 16 + m;
#pragma unroll
            for (int i = 0; i < 4; ++i) {
                float u = fmaxf(acc1[s][ctl][i], 0.f);
                unsigned short uh = f2bf(u);
                int ru = s * 16 + g * 4 + i;
                int sidx = (ru * 128 + col) ^ ((ru & 7) << 3);
                lds[sidx] = (short)uh;
                lds[8192 + sidx] = (short)f2bf(u - bf2f(uh));
            }
        }
    }
#pragma unroll
    for (int ctl = 0; ctl < 2; ++ctl) {
        int col = wv * 32 + ctl * 16 + m;
#pragma unroll
        for (int kc = 0; kc < 4; ++kc) {
            wh[ctl][kc] = *(const bf16x8*)(W2Hi + col * 128 + kc * 32 + g * 8);
            wl[ctl][kc] = *(const bf16x8*)(W2Lo + col * 128 + kc * 32 + g * 8);
        }
    }
    __syncthreads();

#pragma unroll
    for (int s = 0; s < 4; ++s) {
        int rloc = s * 16 + m;
        bf16x8 uHi[4], uLo[4];
#pragma unroll
        for (int kc = 0; kc < 4; ++kc) {
            int idx = (rloc * 128 + kc * 32 + g * 8) ^ ((rloc & 7) << 3);
            uHi[kc] = *(const bf16x8*)(lds + idx);
            uLo[kc] = *(const bf16x8*)(lds + 8192 + idx);
        }
#pragma unroll
        for (int ctl = 0; ctl < 2; ++ctl) {
            int col = wv * 32 + ctl * 16 + m;
            float bv = b2[col];
            f32x4 a = {bv, bv, bv, bv};
#pragma unroll
            for (int kc = 0; kc < 4; ++kc) {
                a = __builtin_amdgcn_mfma_f32_16x16x32_bf16(uHi[kc], wh[ctl][kc], a, 0, 0, 0);
                a = __builtin_amdgcn_mfma_f32_16x16x32_bf16(uLo[kc], wh[ctl][kc], a, 0, 0, 0);
                a = __builtin_amdgcn_mfma_f32_16x16x32_bf16(uHi[kc], wl[ctl][kc], a, 0, 0, 0);
            }
#pragma unroll
            for (int i = 0; i < 4; ++i) {
                int row = rowBase + s * 16 + g * 4 + i;
                if (row < NN) {
                    float v = fmaxf(a[i] + racc[s][ctl][i], 0.f);
                    hout[(size_t)row * 128 + col] = v;
                    hbout[(size_t)row * 128 + col] = (short)f2bf(v);
                }
            }
        }
    }
}

// ---------------- fused mean-pool + FC head ----------------
static __device__ __forceinline__ int lbound(const int* __restrict__ a, int n, int v) {
    int lo = 0, hi = n;
    while (lo < hi) {
        int mid = (lo + hi) >> 1;
        if (a[mid] < v) lo = mid + 1;
        else hi = mid;
    }
    return lo;
}

__global__ void head_kernel(const float* __restrict__ h, const int* __restrict__ batch,
                            const float* __restrict__ fW1, const float* __restrict__ fb1,
                            const float* __restrict__ fW2, const float* __restrict__ fb2,
                            float* __restrict__ out) {
    __shared__ float sp[128];
    __shared__ float su[128];
    __shared__ int sr[2];
    int g = blockIdx.x, t = threadIdx.x;
    if (t == 0) sr[0] = lbound(batch, NN, g);
    if (t == 1) sr[1] = lbound(batch, NN, g + 1);
    __syncthreads();
    int beg = sr[0], end = sr[1];
    float acc = 0.f;
    for (int i = beg; i < end; ++i) acc += h[(size_t)i * 128 + t];
    sp[t] = acc / (float)max(end - beg, 1);
    __syncthreads();
    float a = fb1[t];
#pragma unroll 4
    for (int k = 0; k < 128; ++k) a = fmaf(sp[k], fW1[k * 128 + t], a);
    a = a > 0.f ? a : 0.01f * a;
    su[t] = a * fW2[t];
    __syncthreads();
    for (int s2 = 64; s2 > 0; s2 >>= 1) {
        if (t < s2) su[t] += su[t + s2];
        __syncthreads();
    }
    if (t == 0) out[g] = su[0] + fb2[0];
}

extern "C" void kernel_launch(void* const* d_in, const int* in_sizes, int n_in,
                              void* d_out, int out_size, void* d_ws, size_t ws_size,
                              hipStream_t stream) {
    const float* x = (const float*)d_in[0];
    const int* eidx = (const int*)d_in[1];
    const int* src = eidx;
    const int* dst = eidx + NE;
    const int* batch = (const int*)d_in[2];
    const float* l0_W1 = (const float*)d_in[3];
    const float* l0_b1 = (const float*)d_in[4];
    const float* l0_W2 = (const float*)d_in[5];
    const float* l0_b2 = (const float*)d_in[6];
    const float* l0_Wres = (const float*)d_in[7];
    const float* Ws1 = (const float*)d_in[8];
    const float* bs1 = (const float*)d_in[9];
    const float* Ws2 = (const float*)d_in[10];
    const float* bs2 = (const float*)d_in[11];
    const float* fW1 = (const float*)d_in[12];
    const float* fb1 = (const float*)d_in[13];
    const float* fW2 = (const float*)d_in[14];
    const float* fb2 = (const float*)d_in[15];
    float* out = (float*)d_out;

    size_t used = 0;
    auto alloc = [&](size_t bytes) -> char* {
        char* r = (char*)d_ws + used;
        used = (used + bytes + 255) & ~(size_t)255;
        return r;
    };
    float* A = (float*)alloc((size_t)NN * HID * 4);  // t buffer
    float* B = (float*)alloc((size_t)NN * HID * 4);  // h ping
    float* C = (float*)alloc((size_t)NN * HID * 4);  // h pong
    int* bcur = (int*)alloc((size_t)NBK * 4);
    int* row_beg = (int*)alloc((size_t)NN * 4);
    int* row_end = (int*)alloc((size_t)NN * 4);
    int* esrc = (int*)alloc((size_t)NBK * BCAP * 4);
    // bedge (4.0MB) aliases xb (6.4MB): bedge dead after build_csr
    char* shared_region = alloc((size_t)NN * IND * 2 > (size_t)NBK * BCAP * 4
                                    ? (size_t)NN * IND * 2
                                    : (size_t)NBK * BCAP * 4);
    unsigned int* bedge = (unsigned int*)shared_region;
    short* xb = (short*)shared_region;
    short* wresHi = (short*)alloc(128 * 64 * 2);
    short* wresLo = (short*)alloc(128 * 64 * 2);
    short* w1Hi = (short*)alloc(128 * 64 * 2);
    short* w1Lo = (short*)alloc(128 * 64 * 2);
    short* w2Hi = (short*)alloc(128 * 128 * 2);
    short* w2Lo = (short*)alloc(128 * 128 * 2);
    short* ws1Hi = (short*)alloc(3 * 128 * 128 * 2);
    short* ws1Lo = (short*)alloc(3 * 128 * 128 * 2);
    short* ws2Hi = (short*)alloc(3 * 128 * 128 * 2);
    short* ws2Lo = (short*)alloc(3 * 128 * 128 * 2);
    short* hb = (short*)alloc((size_t)NN * HID * 2);

    hipMemsetAsync(bcur, 0, (size_t)NBK * 4, stream);

    const int GB = (NN + 63) / 64;   // 782
    const int AGGB = (NN + 3) / 4;   // 12500

    convert_all<<<512, 256, 0, stream>>>(l0_Wres, l0_W1, l0_W2, Ws1, Ws2, wresHi, wresLo, w1Hi,
                                         w1Lo, w2Hi, w2Lo, ws1Hi, ws1Lo, ws2Hi, ws2Lo);

    bin_kernel<<<(NE + 4095) / 4096, 256, 0, stream>>>(src, dst, bcur, bedge);
    build_csr_kernel<<<NBK, 256, 0, stream>>>(bedge, bcur, row_beg, row_end, esrc);

    to_bf16_kernel<<<(NN * IND + 255) / 256, 256, 0, stream>>>(x, xb, NN * IND);

    // layer 0: t0 = x + agg(x) -> A; h0 = fused0(A, x) -> B (+ hb)
    agg64b_kernel<<<AGGB, 256, 0, stream>>>((const unsigned short*)xb, x, row_beg, row_end, esrc,
                                            A);
    fused0<<<GB, 256, 0, stream>>>(A, x, w1Hi, w1Lo, l0_b1, w2Hi, w2Lo, l0_b2, wresHi, wresLo, B,
                                   hb);

    // layers 1..3: t = h + agg(hb) -> A; h' = fused2(A, h) -> ping-pong (+ hb)
    float* hcur = B;
    float* hnxt = C;
    for (int l = 0; l < 3; ++l) {
        agg128b_kernel<<<AGGB, 256, 0, stream>>>((const unsigned int*)hb, hcur, row_beg, row_end,
                                                 esrc, A);
        fused2<<<GB, 256, 0, stream>>>(A, hcur, ws1Hi + (size_t)l * 16384,
                                       ws1Lo + (size_t)l * 16384, bs1 + (size_t)l * HID,
                                       ws2Hi + (size_t)l * 16384, ws2Lo + (size_t)l * 16384,
                                       bs2 + (size_t)l * HID, hnxt, hb);
        float* t2 = hcur;
        hcur = hnxt;
        hnxt = t2;
    }

    head_kernel<<<NG, 128, 0, stream>>>(hcur, batch, fW1, fb1, fW2, fb2, out);
}